// Round 5
// baseline (104.130 us; speedup 1.0000x reference)
//
#include <hip/hip_runtime.h>

#define NCLS 21
#define HW (512 * 512)
#define HW2 (HW / 2)                   // 131072 float2 per (b,c) plane
#define NB 8
#define NPIX (NB * HW)                 // 2097152
#define NPIX2 (NPIX / 2)               // 1048576 float2 pixel-pairs
#define NPIX4 (NPIX / 4)               // 524288 float4 pixel-quads
#define NBLK 2048
#define THREADS 256
#define GSIZE1 (NBLK * THREADS)        // 524288
#define IT1 (NPIX2 / GSIZE1)           // 2 float2-pairs per thread (4 pixels)
#define TOTAL_ELEMS ((long long)NPIX * NCLS)

// ws layout:
//   [0      ..  8K)   float bmin[2048]
//   [8K     .. 16K)   float bmax[2048]
//   [16K    .. 16K+4) int   counter
//   [16448  .. 32832) double partial[2048]
//   [65536  .. +8MB)  float sigraw[NPIX]
//   [next 8MB)        float S[NPIX]

__global__ __launch_bounds__(256) void lasd_pass1(const float2* __restrict__ in2,
                                                  const int2* __restrict__ tgt2,
                                                  float2* __restrict__ sigraw2,
                                                  float2* __restrict__ S2,
                                                  float* __restrict__ bmin,
                                                  float* __restrict__ bmax,
                                                  int* __restrict__ counter) {
    const int tid = blockIdx.x * THREADS + threadIdx.x;
    if (tid == 0) *counter = 0;    // reset for pass2's last-block detection

    float lmin = 1e30f, lmax = -1e30f;

#pragma unroll
    for (int it = 0; it < IT1; ++it) {
        int j = tid + it * GSIZE1;          // float2 index over pixels
        int b = j >> 17;                     // j / HW2
        int p2 = j & (HW2 - 1);
        const float2* base = in2 + ((size_t)(b * NCLS) << 17) + p2;

        float2 x[NCLS];
#pragma unroll
        for (int c = 0; c < NCLS; ++c) x[c] = base[(size_t)c << 17];

        float s0 = 0.f, s1 = 0.f;
#pragma unroll
        for (int c = 0; c < NCLS; ++c) { s0 += __expf(x[c].x); s1 += __expf(x[c].y); }
        float inv0 = 1.0f / s0, inv1 = 1.0f / s1;
        float ls0 = __logf(s0), ls1 = __logf(s1);

        int2 tt = tgt2[j];

        float sp0 = 0, sp1 = 0, q0 = 0, q1 = 0, F0 = 0, F1 = 0, ft0 = 0, ft1 = 0;
#pragma unroll
        for (int c = 0; c < NCLS; ++c) {
            float p0 = __expf(x[c].x) * inv0 + 1e-8f;        // softmax + EPS
            float p1 = __expf(x[c].y) * inv1 + 1e-8f;
            float om0 = 1.0f - p0, om1 = 1.0f - p1;
            float f0 = -0.25f * om0 * om0 * (x[c].x - ls0);  // log p = x - log s
            float f1 = -0.25f * om1 * om1 * (x[c].y - ls1);
            sp0 += p0; sp1 += p1;
            q0 = fmaf(p0, p0, q0); q1 = fmaf(p1, p1, q1);
            F0 += f0; F1 += f1;
            if (c == tt.x) ft0 = f0;
            if (c == tt.y) ft1 = f1;
        }

        float var0 = fmaxf(q0 - sp0 * sp0 * (1.0f / 21.0f), 0.0f);
        float var1 = fmaxf(q1 - sp1 * sp1 * (1.0f / 21.0f), 0.0f);
        float sg0 = sqrtf(var0 * (1.0f / 20.0f));            // ddof=1
        float sg1 = sqrtf(var1 * (1.0f / 20.0f));

        float2 sg; sg.x = sg0; sg.y = sg1;
        sigraw2[j] = sg;
        float2 Sv; Sv.x = ft0 + 1e-6f * F0; Sv.y = ft1 + 1e-6f * F1;
        S2[j] = Sv;
        lmin = fminf(lmin, fminf(sg0, sg1));
        lmax = fmaxf(lmax, fmaxf(sg0, sg1));
    }

#pragma unroll
    for (int off = 32; off > 0; off >>= 1) {
        lmin = fminf(lmin, __shfl_down(lmin, off));
        lmax = fmaxf(lmax, __shfl_down(lmax, off));
    }
    __shared__ float smn[4], smx[4];
    int wid = threadIdx.x >> 6, lane = threadIdx.x & 63;
    if (lane == 0) { smn[wid] = lmin; smx[wid] = lmax; }
    __syncthreads();
    if (threadIdx.x == 0) {
        bmin[blockIdx.x] = fminf(fminf(smn[0], smn[1]), fminf(smn[2], smn[3]));
        bmax[blockIdx.x] = fmaxf(fmaxf(smx[0], smx[1]), fmaxf(smx[2], smx[3]));
    }
}

__global__ __launch_bounds__(256) void lasd_pass2(const float4* __restrict__ sigraw4,
                                                  const float4* __restrict__ S4,
                                                  float* __restrict__ out,    // [0]=loss, [1..]=sigma
                                                  const float* __restrict__ bmin,
                                                  const float* __restrict__ bmax,
                                                  double* __restrict__ partial,
                                                  int* __restrict__ counter) {
    const int wid = threadIdx.x >> 6, lane = threadIdx.x & 63;

    // ---- redundant per-block min/max reduction over 2048 partials ----
    float a = 1e30f, z = -1e30f;
#pragma unroll
    for (int k = 0; k < NBLK / THREADS; ++k) {
        a = fminf(a, bmin[threadIdx.x + k * THREADS]);
        z = fmaxf(z, bmax[threadIdx.x + k * THREADS]);
    }
#pragma unroll
    for (int off = 32; off > 0; off >>= 1) {
        a = fminf(a, __shfl_down(a, off));
        z = fmaxf(z, __shfl_down(z, off));
    }
    __shared__ float smn[4], smx[4];
    __shared__ float s_min, s_max;
    if (lane == 0) { smn[wid] = a; smx[wid] = z; }
    __syncthreads();
    if (threadIdx.x == 0) {
        s_min = fminf(fminf(smn[0], smn[1]), fminf(smn[2], smn[3]));
        s_max = fmaxf(fmaxf(smx[0], smx[1]), fmaxf(smx[2], smx[3]));
    }
    __syncthreads();
    float smin = s_min;
    float rinv = 1.0f / (s_max - smin);

    // ---- normalize + beta*S partial ----
    int j = blockIdx.x * THREADS + threadIdx.x;   // float4 index
    float4 sg = sigraw4[j];
    float4 Sv = S4[j];
    float sraw[4] = {sg.x, sg.y, sg.z, sg.w};
    float S[4] = {Sv.x, Sv.y, Sv.z, Sv.w};
    float lsum = 0.0f;
#pragma unroll
    for (int k = 0; k < 4; ++k) {
        float t = (sraw[k] - smin) * rinv;
        out[1 + 4 * j + k] = t;
        lsum += (__expf(-t) + 1.0f) * S[k];
    }
#pragma unroll
    for (int off = 32; off > 0; off >>= 1) lsum += __shfl_down(lsum, off);
    __shared__ float shs[4];
    if (lane == 0) shs[wid] = lsum;
    __syncthreads();
    __shared__ bool s_last;
    if (threadIdx.x == 0) {
        partial[blockIdx.x] = (double)(shs[0] + shs[1] + shs[2] + shs[3]);
        __threadfence();                               // partials visible device-wide
        int old = atomicAdd(counter, 1);               // device-scope
        s_last = (old == NBLK - 1);
    }
    __syncthreads();

    // ---- last finishing block reduces 2048 doubles -> loss ----
    if (s_last) {
        double acc = 0.0;
#pragma unroll
        for (int k = 0; k < NBLK / THREADS; ++k)
            acc += ((volatile const double*)partial)[threadIdx.x + k * THREADS];
#pragma unroll
        for (int off = 32; off > 0; off >>= 1) acc += __shfl_down(acc, off);
        __shared__ double shd[4];
        if (lane == 0) shd[wid] = acc;
        __syncthreads();
        if (threadIdx.x == 0)
            out[0] = (float)((shd[0] + shd[1] + shd[2] + shd[3]) / (double)TOTAL_ELEMS);
    }
}

extern "C" void kernel_launch(void* const* d_in, const int* in_sizes, int n_in,
                              void* d_out, int out_size, void* d_ws, size_t ws_size,
                              hipStream_t stream) {
    const float2* logits2 = (const float2*)d_in[0];
    const int2* target2 = (const int2*)d_in[1];
    float* out = (float*)d_out;
    char* ws = (char*)d_ws;

    float* bmin = (float*)ws;                         // 2048 f
    float* bmax = (float*)(ws + 8192);                // 2048 f
    int* counter = (int*)(ws + 16384);
    double* partial = (double*)(ws + 16448);          // 2048 d
    float* sigraw = (float*)(ws + 65536);             // 8 MB
    float* S = (float*)(ws + 65536 + (size_t)NPIX * 4);  // 8 MB

    lasd_pass1<<<NBLK, THREADS, 0, stream>>>(logits2, target2,
                                             (float2*)sigraw, (float2*)S,
                                             bmin, bmax, counter);
    lasd_pass2<<<NBLK, THREADS, 0, stream>>>((const float4*)sigraw, (const float4*)S,
                                             out, bmin, bmax, partial, counter);
}

// Round 6
// 41.847 us; speedup vs baseline: 2.4884x; 2.4884x over previous
//
#include <hip/hip_runtime.h>
#include <hip/hip_fp16.h>

#define NCLS 21
#define HW (512 * 512)
#define HW2 (HW / 2)                   // 131072 float2 per (b,c) plane
#define NB 8
#define NPIX (NB * HW)                 // 2097152
#define NPIX2 (NPIX / 2)               // 1048576 pixel-pairs
#define NPIX4 (NPIX / 4)               // 524288 pixel-quads
#define NBLK1 (NPIX2 / 256)            // 4096 blocks pass1
#define NBLK2 (NPIX4 / 256)            // 2048 blocks pass2
#define TOTAL_ELEMS ((long long)NPIX * NCLS)

// ws layout:
//   [0     .. 16K)  float bmin[4096]
//   [16K   .. 32K)  float bmax[4096]
//   [32K   .. 48K)  double partial[2048]
//   [64K   .. +8MB) __half2 sigS[NPIX]  (x=sigma_raw fp16, y=S fp16)

union HU { __half2 h; unsigned int u; };

// Pass 1: single logits read; softmax stats + focal; packed (sig,S) fp16;
// per-block min/max partials. No atomics, no fences.
__global__ __launch_bounds__(256) void lasd_pass1(const float2* __restrict__ in2,
                                                  const int2* __restrict__ tgt2,
                                                  uint2* __restrict__ sigS2,
                                                  float* __restrict__ bmin,
                                                  float* __restrict__ bmax) {
    int j = blockIdx.x * 256 + threadIdx.x;    // pixel-pair index
    int b = j >> 17;                            // j / HW2
    int p2 = j & (HW2 - 1);
    const float2* base = in2 + ((size_t)(b * NCLS) << 17) + p2;

    float2 x[NCLS];
#pragma unroll
    for (int c = 0; c < NCLS; ++c) x[c] = base[(size_t)c << 17];

    float s0 = 0.f, s1 = 0.f;
#pragma unroll
    for (int c = 0; c < NCLS; ++c) { s0 += __expf(x[c].x); s1 += __expf(x[c].y); }
    float inv0 = 1.0f / s0, inv1 = 1.0f / s1;
    float ls0 = __logf(s0), ls1 = __logf(s1);

    int2 tt = tgt2[j];

    float sp0 = 0, sp1 = 0, q0 = 0, q1 = 0, F0 = 0, F1 = 0, ft0 = 0, ft1 = 0;
#pragma unroll
    for (int c = 0; c < NCLS; ++c) {
        float p0 = __expf(x[c].x) * inv0 + 1e-8f;        // softmax + EPS
        float p1 = __expf(x[c].y) * inv1 + 1e-8f;
        float om0 = 1.0f - p0, om1 = 1.0f - p1;
        float f0 = -0.25f * om0 * om0 * (x[c].x - ls0);  // log p = x - log s
        float f1 = -0.25f * om1 * om1 * (x[c].y - ls1);
        sp0 += p0; sp1 += p1;
        q0 = fmaf(p0, p0, q0); q1 = fmaf(p1, p1, q1);
        F0 += f0; F1 += f1;
        if (c == tt.x) ft0 = f0;
        if (c == tt.y) ft1 = f1;
    }

    float var0 = fmaxf(q0 - sp0 * sp0 * (1.0f / 21.0f), 0.0f);
    float var1 = fmaxf(q1 - sp1 * sp1 * (1.0f / 21.0f), 0.0f);
    float sg0 = sqrtf(var0 * (1.0f / 20.0f));            // ddof=1
    float sg1 = sqrtf(var1 * (1.0f / 20.0f));
    float S0 = ft0 + 1e-6f * F0;
    float S1 = ft1 + 1e-6f * F1;

    HU h0, h1;
    h0.h.x = __float2half_rn(sg0); h0.h.y = __float2half_rn(S0);
    h1.h.x = __float2half_rn(sg1); h1.h.y = __float2half_rn(S1);
    uint2 pk; pk.x = h0.u; pk.y = h1.u;
    sigS2[j] = pk;

    // min/max over the ROUNDED sigmas (consistent with what pass2 reads)
    float r0 = __half2float(h0.h.x), r1 = __half2float(h1.h.x);
    float lmin = fminf(r0, r1), lmax = fmaxf(r0, r1);
#pragma unroll
    for (int off = 32; off > 0; off >>= 1) {
        lmin = fminf(lmin, __shfl_down(lmin, off));
        lmax = fmaxf(lmax, __shfl_down(lmax, off));
    }
    __shared__ float smn[4], smx[4];
    int wid = threadIdx.x >> 6, lane = threadIdx.x & 63;
    if (lane == 0) { smn[wid] = lmin; smx[wid] = lmax; }
    __syncthreads();
    if (threadIdx.x == 0) {
        bmin[blockIdx.x] = fminf(fminf(smn[0], smn[1]), fminf(smn[2], smn[3]));
        bmax[blockIdx.x] = fmaxf(fmaxf(smx[0], smx[1]), fmaxf(smx[2], smx[3]));
    }
}

// Pass 2: redundant per-block min/max reduce (L2/L3-served, no fence);
// normalize sigma -> out; per-block beta*S partial sums.
__global__ __launch_bounds__(256) void lasd_pass2(const uint4* __restrict__ sigS4,
                                                  float* __restrict__ out,     // [1..] sigma
                                                  const float4* __restrict__ bmin4,
                                                  const float4* __restrict__ bmax4,
                                                  double* __restrict__ partial) {
    const int wid = threadIdx.x >> 6, lane = threadIdx.x & 63;

    float a = 1e30f, z = -1e30f;
#pragma unroll
    for (int k = 0; k < NBLK1 / 4 / 256; ++k) {          // 4096 floats as 1024 float4
        float4 v = bmin4[threadIdx.x + k * 256];
        float4 w = bmax4[threadIdx.x + k * 256];
        a = fminf(a, fminf(fminf(v.x, v.y), fminf(v.z, v.w)));
        z = fmaxf(z, fmaxf(fmaxf(w.x, w.y), fmaxf(w.z, w.w)));
    }
#pragma unroll
    for (int off = 32; off > 0; off >>= 1) {
        a = fminf(a, __shfl_down(a, off));
        z = fmaxf(z, __shfl_down(z, off));
    }
    __shared__ float smn[4], smx[4];
    __shared__ float s_min, s_rinv;
    if (lane == 0) { smn[wid] = a; smx[wid] = z; }
    __syncthreads();
    if (threadIdx.x == 0) {
        float mn = fminf(fminf(smn[0], smn[1]), fminf(smn[2], smn[3]));
        float mx = fmaxf(fmaxf(smx[0], smx[1]), fmaxf(smx[2], smx[3]));
        s_min = mn;
        s_rinv = 1.0f / (mx - mn);
    }
    __syncthreads();
    float smin = s_min, rinv = s_rinv;

    int j = blockIdx.x * 256 + threadIdx.x;              // pixel-quad index
    uint4 pk = sigS4[j];
    unsigned int w[4] = {pk.x, pk.y, pk.z, pk.w};
    float lsum = 0.0f;
#pragma unroll
    for (int k = 0; k < 4; ++k) {
        HU cv; cv.u = w[k];
        float sg = __half2float(cv.h.x);
        float S = __half2float(cv.h.y);
        float t = (sg - smin) * rinv;
        out[1 + 4 * j + k] = t;
        lsum += (__expf(-t) + 1.0f) * S;
    }
#pragma unroll
    for (int off = 32; off > 0; off >>= 1) lsum += __shfl_down(lsum, off);
    __shared__ float shs[4];
    if (lane == 0) shs[wid] = lsum;
    __syncthreads();
    if (threadIdx.x == 0)
        partial[blockIdx.x] = (double)(shs[0] + shs[1] + shs[2] + shs[3]);
}

// Final: sum 2048 doubles -> loss
__global__ __launch_bounds__(256) void lasd_finish(const double* __restrict__ partial,
                                                   float* __restrict__ loss_out) {
    double acc = 0.0;
#pragma unroll
    for (int k = 0; k < NBLK2 / 256; ++k)
        acc += partial[threadIdx.x + k * 256];
#pragma unroll
    for (int off = 32; off > 0; off >>= 1) acc += __shfl_down(acc, off);
    __shared__ double sh[4];
    int wid = threadIdx.x >> 6, lane = threadIdx.x & 63;
    if (lane == 0) sh[wid] = acc;
    __syncthreads();
    if (threadIdx.x == 0)
        loss_out[0] = (float)((sh[0] + sh[1] + sh[2] + sh[3]) / (double)TOTAL_ELEMS);
}

extern "C" void kernel_launch(void* const* d_in, const int* in_sizes, int n_in,
                              void* d_out, int out_size, void* d_ws, size_t ws_size,
                              hipStream_t stream) {
    const float2* logits2 = (const float2*)d_in[0];
    const int2* target2 = (const int2*)d_in[1];
    float* out = (float*)d_out;                  // out[0]=loss, out[1..]=sigma
    char* ws = (char*)d_ws;

    float* bmin = (float*)ws;                    // 4096 f
    float* bmax = (float*)(ws + 16384);          // 4096 f
    double* partial = (double*)(ws + 32768);     // 2048 d
    uint2* sigS = (uint2*)(ws + 65536);          // 8 MB packed half2 per pixel

    lasd_pass1<<<NBLK1, 256, 0, stream>>>(logits2, target2, sigS, bmin, bmax);
    lasd_pass2<<<NBLK2, 256, 0, stream>>>((const uint4*)sigS, out,
                                          (const float4*)bmin, (const float4*)bmax,
                                          partial);
    lasd_finish<<<1, 256, 0, stream>>>(partial, out);
}